// Round 5
// baseline (1238.371 us; speedup 1.0000x reference)
//
#include <hip/hip_runtime.h>

namespace {

typedef unsigned short u16;
typedef __attribute__((__ext_vector_type__(2))) float f32x2;
typedef __attribute__((__ext_vector_type__(4))) float f32x4;

constexpr int Un = 100000;
constexpr int In = 50000;
constexpr int Nn = 150000;
constexpr int D  = 64;
constexpr int Ln = 3;
constexpr int En = 2000000;
constexpr int CHUNK = 1024;
constexpr int NB = (Nn + CHUNK - 1) / CHUNK;  // 147 scan blocks
constexpr int DCAP = 128;                     // degree histogram cap
constexpr int NW = Nn / 8;                    // 18750 waves (8 rows/wave)

__device__ __forceinline__ u16 f2bf(float f) {
    unsigned u = __float_as_uint(f);
    unsigned r = (u + 0x7FFFu + ((u >> 16) & 1u)) >> 16;
    return (u16)r;
}
__device__ __forceinline__ float bflo(unsigned u) {
    return __uint_as_float(u << 16);
}
__device__ __forceinline__ float bfhi(unsigned u) {
    return __uint_as_float(u & 0xFFFF0000u);
}
__device__ __forceinline__ unsigned pack2(float lo, float hi) {
    return (unsigned)f2bf(lo) | ((unsigned)f2bf(hi) << 16);
}

// packed dual-FP32 FMA / ADD (CDNA VOP3P)
__device__ __forceinline__ f32x2 pkfma(f32x2 a, f32x2 b, f32x2 c) {
    f32x2 d;
    asm("v_pk_fma_f32 %0, %1, %2, %3" : "=v"(d) : "v"(a), "v"(b), "v"(c));
    return d;
}
__device__ __forceinline__ f32x2 pkadd(f32x2 a, f32x2 b) {
    f32x2 d;
    asm("v_pk_add_f32 %0, %1, %2" : "=v"(d) : "v"(a), "v"(b));
    return d;
}

// sum across each aligned 8-lane group, pure-VALU DPP (no LDS pipe)
__device__ __forceinline__ float dpp_add8(float x) {
    x += __uint_as_float((unsigned)__builtin_amdgcn_update_dpp(
        0, (int)__float_as_uint(x), 0xB1, 0xF, 0xF, true));
    x += __uint_as_float((unsigned)__builtin_amdgcn_update_dpp(
        0, (int)__float_as_uint(x), 0x4E, 0xF, 0xF, true));
    x += __uint_as_float((unsigned)__builtin_amdgcn_update_dpp(
        0, (int)__float_as_uint(x), 0x141, 0xF, 0xF, true));
    return x;
}

__device__ __forceinline__ void unp8(uint4 q, f32x2* o) {
    o[0].x = bflo(q.x); o[0].y = bfhi(q.x);
    o[1].x = bflo(q.y); o[1].y = bfhi(q.y);
    o[2].x = bflo(q.z); o[2].y = bfhi(q.z);
    o[3].x = bflo(q.w); o[3].y = bfhi(q.w);
}

// count AND record per-edge within-row offset -> fill needs no atomics.
__global__ void count_kernel(const int* __restrict__ rows, int* __restrict__ deg,
                             int* __restrict__ eoff) {
    int e = blockIdx.x * blockDim.x + threadIdx.x;
    if (e < En) eoff[e] = atomicAdd(&deg[rows[e]], 1);
}

__global__ void scan_partial(const int* __restrict__ deg, float* __restrict__ d_is,
                             int* __restrict__ bsum) {
    int tid = threadIdx.x;
    int base = blockIdx.x * CHUNK + tid * 4;
    int s = 0;
#pragma unroll
    for (int i = 0; i < 4; ++i) {
        int idx = base + i;
        if (idx < Nn) {
            int d = deg[idx];
            s += d;
            d_is[idx] = d > 0 ? rsqrtf((float)d) : 0.f;
        }
    }
    __shared__ int sh[256];
    sh[tid] = s;
    __syncthreads();
    for (int o = 128; o > 0; o >>= 1) {
        if (tid < o) sh[tid] += sh[tid + o];
        __syncthreads();
    }
    if (tid == 0) bsum[blockIdx.x] = sh[0];
}

__global__ void scan_top(int* __restrict__ bsum, int* __restrict__ row_ptr) {
    __shared__ int sh[256];
    int tid = threadIdx.x;
    int v = (tid < NB) ? bsum[tid] : 0;
    sh[tid] = v;
    __syncthreads();
    for (int o = 1; o < 256; o <<= 1) {
        int t = (tid >= o) ? sh[tid - o] : 0;
        __syncthreads();
        sh[tid] += t;
        __syncthreads();
    }
    if (tid < NB) bsum[tid] = sh[tid] - v;  // exclusive
    if (tid == 255) row_ptr[Nn] = sh[255];  // == En
}

__global__ void scan_final(const int* __restrict__ deg, const int* __restrict__ bsum,
                           int* __restrict__ row_ptr) {
    int tid = threadIdx.x;
    int base = blockIdx.x * CHUNK + tid * 4;
    int v[4];
    int ts = 0;
#pragma unroll
    for (int i = 0; i < 4; ++i) {
        int idx = base + i;
        v[i] = (idx < Nn) ? deg[idx] : 0;
        ts += v[i];
    }
    __shared__ int sh[256];
    sh[tid] = ts;
    __syncthreads();
    for (int o = 1; o < 256; o <<= 1) {
        int t = (tid >= o) ? sh[tid - o] : 0;
        __syncthreads();
        sh[tid] += t;
        __syncthreads();
    }
    int excl = bsum[blockIdx.x] + sh[tid] - ts;
#pragma unroll
    for (int i = 0; i < 4; ++i) {
        int idx = base + i;
        if (idx < Nn) row_ptr[idx] = excl;
        excl += v[i];
    }
}

// atomic-free scatter; stores BYTE offsets (c * 128)
__global__ void fill_kernel(const int* __restrict__ rows, const int* __restrict__ cols,
                            const int* __restrict__ row_ptr, const int* __restrict__ eoff,
                            int* __restrict__ col_off) {
    int e = blockIdx.x * blockDim.x + threadIdx.x;
    if (e >= En) return;
    col_off[row_ptr[rows[e]] + eoff[e]] = cols[e] << 7;
}

// ---- degree-sorting (counting sort) ----
__global__ void hist_kernel(const int* __restrict__ deg, int* __restrict__ hist) {
    __shared__ int lh[DCAP];
    int tid = threadIdx.x;
    if (tid < DCAP) lh[tid] = 0;
    __syncthreads();
    int i = blockIdx.x * 256 + tid;
    if (i < Nn) atomicAdd(&lh[min(deg[i], DCAP - 1)], 1);
    __syncthreads();
    if (tid < DCAP) {
        int v = lh[tid];
        if (v) atomicAdd(&hist[tid], v);
    }
}

__global__ void hist_scan(int* __restrict__ hist) {  // 1 block x 128
    __shared__ int sh[DCAP];
    int tid = threadIdx.x;
    int v = hist[tid];
    sh[tid] = v;
    __syncthreads();
    for (int o = 1; o < DCAP; o <<= 1) {
        int t = (tid >= o) ? sh[tid - o] : 0;
        __syncthreads();
        sh[tid] += t;
        __syncthreads();
    }
    hist[tid] = sh[tid] - v;  // exclusive
}

// scatter rows into degree-sorted order; pack per-row record:
// srt[p] = {row_ptr[r], row_ptr[r+1], bits(d_is[r]), r}
__global__ void perm_kernel(const int* __restrict__ deg, const int* __restrict__ row_ptr,
                            const float* __restrict__ d_is, int* __restrict__ hist,
                            int4* __restrict__ srt) {
    int i = blockIdx.x * 256 + threadIdx.x;
    if (i >= Nn) return;
    int p = atomicAdd(&hist[min(deg[i], DCAP - 1)], 1);
    int4 v;
    v.x = row_ptr[i];
    v.y = row_ptr[i + 1];
    v.z = __float_as_int(d_is[i]);
    v.w = i;
    srt[p] = v;
}

// emb0 -> acc (f32), cur0 (bf16), S0 = d_is*emb0 (bf16, prescaled for spmm)
__global__ void init_kernel(const float* __restrict__ ue, const float* __restrict__ ie,
                            const float* __restrict__ d_is,
                            float* __restrict__ out, u16* __restrict__ cur,
                            u16* __restrict__ S) {
    int i = (blockIdx.x * 256 + threadIdx.x) * 4;
    if (i >= Nn * D) return;
    const float* src = (i < Un * D) ? (ue + i) : (ie + (i - Un * D));
    float4 v = *(const float4*)src;
    *(float4*)(out + i) = v;
    ushort4 q;
    q.x = f2bf(v.x); q.y = f2bf(v.y); q.z = f2bf(v.z); q.w = f2bf(v.w);
    *(ushort4*)(cur + i) = q;
    float ds = d_is[i >> 6];
    ushort4 qs;
    qs.x = f2bf(v.x * ds); qs.y = f2bf(v.y * ds);
    qs.z = f2bf(v.z * ds); qs.w = f2bf(v.w * ds);
    *(ushort4*)(S + i) = qs;
}

// 8 rows per wave, one 8-lane group per row (degree-sorted -> low divergence).
// Lane l holds dims 8l..8l+7. Serial edge loop per group; NO cross-group
// reduction; all 64 lanes store. Gathers prescaled S rows -> load + pk_add.
// Outputs Qn = gnn/||gnn|| and normv_s[wb] (sorted order) = max(||gnn||,1e-12).
__global__ __launch_bounds__(256) void spmm_gnn(const u16* __restrict__ S_,
                                                u16* __restrict__ Qn_,
                                                const int4* __restrict__ srt,
                                                const int* __restrict__ col_off,
                                                float* __restrict__ normv_s) {
    int w = (blockIdx.x * 256 + threadIdx.x) >> 6;
    if (w >= NW) return;
    int lane = threadIdx.x & 63;
    int g = lane >> 3, l = lane & 7;
    unsigned l16 = (unsigned)l * 16u;
    int wb = w * 8 + g;
    int4 q4 = srt[wb];
    int s = q4.x, t = q4.y;
    float dr = __int_as_float(q4.z);
    int r = q4.w;
    const char* pS = (const char*)S_;
    f32x2 z; z.x = 0.f; z.y = 0.f;
    f32x2 a2[4] = {z, z, z, z};
#pragma unroll 2
    for (int j = s; j < t; ++j) {
        unsigned off = (unsigned)col_off[j];
        uint4 q = *(const uint4*)(pS + (off + l16));
        f32x2 x2[4];
        unp8(q, x2);
#pragma unroll
        for (int p = 0; p < 4; ++p) a2[p] = pkadd(a2[p], x2[p]);
    }
    float sq = 0.f;
#pragma unroll
    for (int p = 0; p < 4; ++p) {
        sq = fmaf(a2[p].x, a2[p].x, sq);
        sq = fmaf(a2[p].y, a2[p].y, sq);
    }
    sq = dpp_add8(sq);
    float gn = dr * sqrtf(sq);          // ||gnn||  (gnn = dr * a)
    float nrm = fmaxf(gn, 1e-12f);
    float scale = dr / nrm;             // Qn = a * scale
    if (l == 0) normv_s[wb] = nrm;
    unsigned ro = ((unsigned)r << 7) + l16;
    uint4 on;
    on.x = pack2(a2[0].x * scale, a2[0].y * scale);
    on.y = pack2(a2[1].x * scale, a2[1].y * scale);
    on.z = pack2(a2[2].x * scale, a2[2].y * scale);
    on.w = pack2(a2[3].x * scale, a2[3].y * scale);
    *(uint4*)((char*)Qn_ + ro) = on;
}

// merged score+fine, 8 rows/wave. Dot over pre-normalized Qn: sc = 0.5d+0.5.
// gnn[r] reconstructed as Qn[r]*normv. All 64 lanes store C/S/acc/fine.
__global__ __launch_bounds__(256) void score_fine_kernel(const u16* __restrict__ A_,
                                                         const u16* __restrict__ Qn_,
                                                         u16* __restrict__ C_,
                                                         u16* __restrict__ S_,
                                                         const float* __restrict__ normv_s,
                                                         const int4* __restrict__ srt,
                                                         const int* __restrict__ col_off,
                                                         float* __restrict__ out, int layer) {
    int w = (blockIdx.x * 256 + threadIdx.x) >> 6;
    if (w >= NW) return;
    int lane = threadIdx.x & 63;
    int g = lane >> 3, l = lane & 7;
    unsigned l16 = (unsigned)l * 16u;
    int wb = w * 8 + g;
    int4 q4 = srt[wb];
    int s = q4.x, t = q4.y;
    float dsr = __int_as_float(q4.z);
    int r = q4.w;
    float nrm = normv_s[wb];
    const char* pQn = (const char*)Qn_;
    const char* pA  = (const char*)A_;
    unsigned ro = ((unsigned)r << 7) + l16;
    uint4 qbn = *(const uint4*)(pQn + ro);
    f32x2 b2[4];
    unp8(qbn, b2);
    f32x2 z; z.x = 0.f; z.y = 0.f;
    f32x2 facc[4] = {z, z, z, z};
    float rowsum = 0.f;
#pragma unroll 2
    for (int j = s; j < t; ++j) {
        unsigned off = (unsigned)col_off[j];
        unsigned vo = off + l16;
        uint4 qx = *(const uint4*)(pQn + vo);
        uint4 qy = *(const uint4*)(pA + vo);
        f32x2 x2[4];
        unp8(qx, x2);
        f32x2 d2 = pkfma(b2[0], x2[0], z);
        d2 = pkfma(b2[1], x2[1], d2);
        d2 = pkfma(b2[2], x2[2], d2);
        d2 = pkfma(b2[3], x2[3], d2);
        float d = dpp_add8(d2.x + d2.y);   // group-uniform dot
        float sc = fmaf(d, 0.5f, 0.5f);
        rowsum += sc;
        f32x2 y2[4];
        unp8(qy, y2);
        f32x2 sc2; sc2.x = sc; sc2.y = sc;
#pragma unroll
        for (int p = 0; p < 4; ++p) facc[p] = pkfma(sc2, y2[p], facc[p]);
    }
    float di = rowsum > 0.f ? 1.f / rowsum : 0.f;
    float f[8] = {facc[0].x * di, facc[0].y * di, facc[1].x * di, facc[1].y * di,
                  facc[2].x * di, facc[2].y * di, facc[3].x * di, facc[3].y * di};
    float bb[8] = {b2[0].x, b2[0].y, b2[1].x, b2[1].y,
                   b2[2].x, b2[2].y, b2[3].x, b2[3].y};
    float cn[8];
#pragma unroll
    for (int k = 0; k < 8; ++k) cn[k] = fmaf(bb[k], nrm, f[k]);  // gnn + fine
    uint4 qn;
    qn.x = pack2(cn[0], cn[1]); qn.y = pack2(cn[2], cn[3]);
    qn.z = pack2(cn[4], cn[5]); qn.w = pack2(cn[6], cn[7]);
    *(uint4*)((char*)C_ + ro) = qn;
    if (layer != Ln - 1) {  // prescaled cur_new for next layer's spmm
        uint4 qs;
        qs.x = pack2(cn[0] * dsr, cn[1] * dsr);
        qs.y = pack2(cn[2] * dsr, cn[3] * dsr);
        qs.z = pack2(cn[4] * dsr, cn[5] * dsr);
        qs.w = pack2(cn[6] * dsr, cn[7] * dsr);
        *(uint4*)((char*)S_ + ro) = qs;
    }
    float* op = out + (size_t)r * D + l * 8;
    float4 a0 = ((float4*)op)[0], a1 = ((float4*)op)[1];
    a0.x += cn[0]; a0.y += cn[1]; a0.z += cn[2]; a0.w += cn[3];
    a1.x += cn[4]; a1.y += cn[5]; a1.z += cn[6]; a1.w += cn[7];
    ((float4*)op)[0] = a0;
    ((float4*)op)[1] = a1;
    size_t fo;
    if (r < Un)
        fo = (size_t)Nn * D + (size_t)layer * Un * D + (size_t)r * D + l * 8;
    else
        fo = (size_t)Nn * D + (size_t)Ln * Un * D + (size_t)layer * In * D
             + (size_t)(r - Un) * D + l * 8;
    f32x4 f0, f1;
    f0.x = f[0]; f0.y = f[1]; f0.z = f[2]; f0.w = f[3];
    f1.x = f[4]; f1.y = f[5]; f1.z = f[6]; f1.w = f[7];
    __builtin_nontemporal_store(f0, (f32x4*)(out + fo));
    __builtin_nontemporal_store(f1, (f32x4*)(out + fo) + 1);
}

}  // namespace

extern "C" void kernel_launch(void* const* d_in, const int* in_sizes, int n_in,
                              void* d_out, int out_size, void* d_ws, size_t ws_size,
                              hipStream_t stream) {
    const float* user_emb = (const float*)d_in[0];
    const float* item_emb = (const float*)d_in[1];
    const int* rows = (const int*)d_in[2];
    const int* cols = (const int*)d_in[3];
    float* out = (float*)d_out;

    char* ws = (char*)d_ws;
    size_t off = 0;
    auto alloc = [&](size_t bytes) -> void* {
        void* p = ws + off;
        off += (bytes + 255) & ~size_t(255);
        return p;
    };
    u16*   buf0    = (u16*)  alloc((size_t)Nn * D * 2);   // P: cur (plain)
    u16*   buf1    = (u16*)  alloc((size_t)Nn * D * 2);   // R: cur_new (plain)
    u16*   buf2    = (u16*)  alloc((size_t)Nn * D * 2);   // Qn: normalized gnn
    u16*   buf3    = (u16*)  alloc((size_t)Nn * D * 2);   // S: prescaled cur
    int*   col_off = (int*)  alloc((size_t)(En + 8) * 4); // byte offsets c*128
    int*   deg     = (int*)  alloc((size_t)Nn * 4);
    int*   row_ptr = (int*)  alloc((size_t)(Nn + 1) * 4);
    float* d_is    = (float*)alloc((size_t)Nn * 4);
    float* normv_s = (float*)alloc((size_t)Nn * 4);
    int4*  srt     = (int4*) alloc((size_t)Nn * 16);      // sorted row records
    int*   hist    = (int*)  alloc(DCAP * 4);
    int*   bsum    = (int*)  alloc(4096);
    // eoff (8 MB) aliases buf2 (Qn): Qn first written by spmm_gnn layer 0,
    // strictly after fill_kernel has consumed eoff.
    int*   eoff    = (int*)buf2;
    (void)ws_size; (void)in_sizes; (void)n_in; (void)out_size;

    hipMemsetAsync(deg, 0, (size_t)Nn * 4, stream);
    hipMemsetAsync(hist, 0, DCAP * 4, stream);

    const int EB = (En + 255) / 256;
    const int RB256 = (Nn + 255) / 256;  // 586
    count_kernel<<<EB, 256, 0, stream>>>(rows, deg, eoff);
    hist_kernel<<<RB256, 256, 0, stream>>>(deg, hist);
    scan_partial<<<NB, 256, 0, stream>>>(deg, d_is, bsum);
    scan_top<<<1, 256, 0, stream>>>(bsum, row_ptr);
    scan_final<<<NB, 256, 0, stream>>>(deg, bsum, row_ptr);
    hist_scan<<<1, DCAP, 0, stream>>>(hist);
    fill_kernel<<<EB, 256, 0, stream>>>(rows, cols, row_ptr, eoff, col_off);
    perm_kernel<<<RB256, 256, 0, stream>>>(deg, row_ptr, d_is, hist, srt);
    // init after scan_partial (needs d_is for the prescaled S0)
    init_kernel<<<(Nn * D / 4 + 255) / 256, 256, 0, stream>>>(user_emb, item_emb, d_is,
                                                              out, buf0, buf3);

    const int WB = (NW * 64 + 255) / 256;  // 4688 blocks, 4 waves/block, 8 rows/wave
    u16* P = buf0;  // cur (plain)
    u16* R = buf1;  // cur_new (plain)
    u16* Qn = buf2;
    u16* S  = buf3; // prescaled cur for spmm (rewritten by score each layer)
    for (int l = 0; l < Ln; ++l) {
        spmm_gnn<<<WB, 256, 0, stream>>>(S, Qn, srt, col_off, normv_s);
        score_fine_kernel<<<WB, 256, 0, stream>>>(P, Qn, R, S, normv_s, srt,
                                                  col_off, out, l);
        u16* tmp = P; P = R; R = tmp;  // cur_new becomes cur
    }
}

// Round 6
// 810.368 us; speedup vs baseline: 1.5282x; 1.5282x over previous
//
#include <hip/hip_runtime.h>

namespace {

typedef unsigned short u16;
typedef __attribute__((__ext_vector_type__(2))) float f32x2;
typedef __attribute__((__ext_vector_type__(4))) float f32x4;

constexpr int Un = 100000;
constexpr int In = 50000;
constexpr int Nn = 150000;
constexpr int D  = 64;
constexpr int Ln = 3;
constexpr int En = 2000000;
constexpr int CHUNK = 1024;
constexpr int NB = (Nn + CHUNK - 1) / CHUNK;  // 147 scan blocks
constexpr int DCAP = 128;                     // degree histogram cap
constexpr int NW = Nn / 8;                    // 18750 waves (8 rows/wave)

__device__ __forceinline__ u16 f2bf(float f) {
    unsigned u = __float_as_uint(f);
    unsigned r = (u + 0x7FFFu + ((u >> 16) & 1u)) >> 16;
    return (u16)r;
}
__device__ __forceinline__ float bflo(unsigned u) {
    return __uint_as_float(u << 16);
}
__device__ __forceinline__ float bfhi(unsigned u) {
    return __uint_as_float(u & 0xFFFF0000u);
}
__device__ __forceinline__ unsigned pack2(float lo, float hi) {
    return (unsigned)f2bf(lo) | ((unsigned)f2bf(hi) << 16);
}

// packed dual-FP32 FMA / ADD (CDNA VOP3P)
__device__ __forceinline__ f32x2 pkfma(f32x2 a, f32x2 b, f32x2 c) {
    f32x2 d;
    asm("v_pk_fma_f32 %0, %1, %2, %3" : "=v"(d) : "v"(a), "v"(b), "v"(c));
    return d;
}
__device__ __forceinline__ f32x2 pkadd(f32x2 a, f32x2 b) {
    f32x2 d;
    asm("v_pk_add_f32 %0, %1, %2" : "=v"(d) : "v"(a), "v"(b));
    return d;
}

// sum across each aligned 8-lane group, pure-VALU DPP (no LDS pipe)
__device__ __forceinline__ float dpp_add8(float x) {
    x += __uint_as_float((unsigned)__builtin_amdgcn_update_dpp(
        0, (int)__float_as_uint(x), 0xB1, 0xF, 0xF, true));
    x += __uint_as_float((unsigned)__builtin_amdgcn_update_dpp(
        0, (int)__float_as_uint(x), 0x4E, 0xF, 0xF, true));
    x += __uint_as_float((unsigned)__builtin_amdgcn_update_dpp(
        0, (int)__float_as_uint(x), 0x141, 0xF, 0xF, true));
    return x;
}

__device__ __forceinline__ void unp8(uint4 q, f32x2* o) {
    o[0].x = bflo(q.x); o[0].y = bfhi(q.x);
    o[1].x = bflo(q.y); o[1].y = bfhi(q.y);
    o[2].x = bflo(q.z); o[2].y = bfhi(q.z);
    o[3].x = bflo(q.w); o[3].y = bfhi(q.w);
}

// count AND record per-edge within-row offset -> fill needs no atomics.
__global__ void count_kernel(const int* __restrict__ rows, int* __restrict__ deg,
                             int* __restrict__ eoff) {
    int e = blockIdx.x * blockDim.x + threadIdx.x;
    if (e < En) eoff[e] = atomicAdd(&deg[rows[e]], 1);
}

__global__ void scan_partial(const int* __restrict__ deg, float* __restrict__ d_is,
                             int* __restrict__ bsum) {
    int tid = threadIdx.x;
    int base = blockIdx.x * CHUNK + tid * 4;
    int s = 0;
#pragma unroll
    for (int i = 0; i < 4; ++i) {
        int idx = base + i;
        if (idx < Nn) {
            int d = deg[idx];
            s += d;
            d_is[idx] = d > 0 ? rsqrtf((float)d) : 0.f;
        }
    }
    __shared__ int sh[256];
    sh[tid] = s;
    __syncthreads();
    for (int o = 128; o > 0; o >>= 1) {
        if (tid < o) sh[tid] += sh[tid + o];
        __syncthreads();
    }
    if (tid == 0) bsum[blockIdx.x] = sh[0];
}

__global__ void scan_top(int* __restrict__ bsum, int* __restrict__ row_ptr) {
    __shared__ int sh[256];
    int tid = threadIdx.x;
    int v = (tid < NB) ? bsum[tid] : 0;
    sh[tid] = v;
    __syncthreads();
    for (int o = 1; o < 256; o <<= 1) {
        int t = (tid >= o) ? sh[tid - o] : 0;
        __syncthreads();
        sh[tid] += t;
        __syncthreads();
    }
    if (tid < NB) bsum[tid] = sh[tid] - v;  // exclusive
    if (tid == 255) row_ptr[Nn] = sh[255];  // == En
}

__global__ void scan_final(const int* __restrict__ deg, const int* __restrict__ bsum,
                           int* __restrict__ row_ptr) {
    int tid = threadIdx.x;
    int base = blockIdx.x * CHUNK + tid * 4;
    int v[4];
    int ts = 0;
#pragma unroll
    for (int i = 0; i < 4; ++i) {
        int idx = base + i;
        v[i] = (idx < Nn) ? deg[idx] : 0;
        ts += v[i];
    }
    __shared__ int sh[256];
    sh[tid] = ts;
    __syncthreads();
    for (int o = 1; o < 256; o <<= 1) {
        int t = (tid >= o) ? sh[tid - o] : 0;
        __syncthreads();
        sh[tid] += t;
        __syncthreads();
    }
    int excl = bsum[blockIdx.x] + sh[tid] - ts;
#pragma unroll
    for (int i = 0; i < 4; ++i) {
        int idx = base + i;
        if (idx < Nn) row_ptr[idx] = excl;
        excl += v[i];
    }
}

// atomic-free scatter; stores BYTE offsets (c * 128)
__global__ void fill_kernel(const int* __restrict__ rows, const int* __restrict__ cols,
                            const int* __restrict__ row_ptr, const int* __restrict__ eoff,
                            int* __restrict__ col_off) {
    int e = blockIdx.x * blockDim.x + threadIdx.x;
    if (e >= En) return;
    col_off[row_ptr[rows[e]] + eoff[e]] = cols[e] << 7;
}

// ---- contention-free counting sort by degree ----
// per-block 128-bin histogram (LDS only), coalesced write: hp[bin*NB + blk]
__global__ void hist_part(const int* __restrict__ deg, int* __restrict__ hp) {
    __shared__ int lh[DCAP];
    int tid = threadIdx.x;
    if (tid < DCAP) lh[tid] = 0;
    __syncthreads();
    int base = blockIdx.x * CHUNK + tid * 4;
#pragma unroll
    for (int i = 0; i < 4; ++i) {
        int idx = base + i;
        if (idx < Nn) atomicAdd(&lh[min(deg[idx], DCAP - 1)], 1);
    }
    __syncthreads();
    if (tid < DCAP) hp[tid * NB + blockIdx.x] = lh[tid];
}

// single-block exclusive scan of hp[DCAP*NB] (bin-major -> degree-sorted bases)
__global__ void hp_scan(int* __restrict__ hp) {
    constexpr int TOT = DCAP * NB;              // 18816
    constexpr int PER = (TOT + 1023) / 1024;    // 19
    __shared__ int sh[1024];
    int tid = threadIdx.x;
    int base = tid * PER;
    int s = 0;
    for (int i = 0; i < PER; ++i) {
        int idx = base + i;
        if (idx < TOT) s += hp[idx];
    }
    sh[tid] = s;
    __syncthreads();
    for (int o = 1; o < 1024; o <<= 1) {
        int t = (tid >= o) ? sh[tid - o] : 0;
        __syncthreads();
        sh[tid] += t;
        __syncthreads();
    }
    int excl = sh[tid] - s;
    for (int i = 0; i < PER; ++i) {
        int idx = base + i;
        if (idx < TOT) {
            int v = hp[idx];
            hp[idx] = excl;
            excl += v;
        }
    }
}

// rank within (block,bin) via LDS atomics + scanned base -> scatter record
// srt[p] = {row_ptr[r], row_ptr[r+1], bits(d_is[r]), r}
__global__ void perm_scatter(const int* __restrict__ deg, const int* __restrict__ row_ptr,
                             const float* __restrict__ d_is, const int* __restrict__ hp,
                             int4* __restrict__ srt) {
    __shared__ int lh[DCAP];
    __shared__ int lbase[DCAP];
    int tid = threadIdx.x;
    if (tid < DCAP) lh[tid] = 0;
    __syncthreads();
    int base = blockIdx.x * CHUNK + tid * 4;
    int bin[4], rank[4];
#pragma unroll
    for (int i = 0; i < 4; ++i) {
        int idx = base + i;
        if (idx < Nn) {
            bin[i] = min(deg[idx], DCAP - 1);
            rank[i] = atomicAdd(&lh[bin[i]], 1);
        }
    }
    __syncthreads();
    if (tid < DCAP) lbase[tid] = hp[tid * NB + blockIdx.x];
    __syncthreads();
#pragma unroll
    for (int i = 0; i < 4; ++i) {
        int idx = base + i;
        if (idx < Nn) {
            int p = lbase[bin[i]] + rank[i];
            int4 v;
            v.x = row_ptr[idx];
            v.y = row_ptr[idx + 1];
            v.z = __float_as_int(d_is[idx]);
            v.w = idx;
            srt[p] = v;
        }
    }
}

// emb0 -> acc (f32), cur0 (bf16), S0 = d_is*emb0 (bf16, prescaled for spmm)
__global__ void init_kernel(const float* __restrict__ ue, const float* __restrict__ ie,
                            const float* __restrict__ d_is,
                            float* __restrict__ out, u16* __restrict__ cur,
                            u16* __restrict__ S) {
    int i = (blockIdx.x * 256 + threadIdx.x) * 4;
    if (i >= Nn * D) return;
    const float* src = (i < Un * D) ? (ue + i) : (ie + (i - Un * D));
    float4 v = *(const float4*)src;
    *(float4*)(out + i) = v;
    ushort4 q;
    q.x = f2bf(v.x); q.y = f2bf(v.y); q.z = f2bf(v.z); q.w = f2bf(v.w);
    *(ushort4*)(cur + i) = q;
    float ds = d_is[i >> 6];
    ushort4 qs;
    qs.x = f2bf(v.x * ds); qs.y = f2bf(v.y * ds);
    qs.z = f2bf(v.z * ds); qs.w = f2bf(v.w * ds);
    *(ushort4*)(S + i) = qs;
}

// 8 rows per wave, one 8-lane group per row (degree-sorted -> low divergence).
// Lane l holds dims 8l..8l+7. Serial edge loop per group; no cross-group
// reduction; all 64 lanes store. Gathers prescaled S rows -> load + pk_add.
__global__ __launch_bounds__(256) void spmm_gnn(const u16* __restrict__ S_,
                                                u16* __restrict__ Qn_,
                                                const int4* __restrict__ srt,
                                                const int* __restrict__ col_off,
                                                float* __restrict__ normv_s) {
    int w = (blockIdx.x * 256 + threadIdx.x) >> 6;
    if (w >= NW) return;
    int lane = threadIdx.x & 63;
    int g = lane >> 3, l = lane & 7;
    unsigned l16 = (unsigned)l * 16u;
    int wb = w * 8 + g;
    int4 q4 = srt[wb];
    int s = q4.x, t = q4.y;
    float dr = __int_as_float(q4.z);
    int r = q4.w;
    const char* pS = (const char*)S_;
    f32x2 z; z.x = 0.f; z.y = 0.f;
    f32x2 a2[4] = {z, z, z, z};
#pragma unroll 4
    for (int j = s; j < t; ++j) {
        unsigned off = (unsigned)col_off[j];
        uint4 q = *(const uint4*)(pS + (off + l16));
        f32x2 x2[4];
        unp8(q, x2);
#pragma unroll
        for (int p = 0; p < 4; ++p) a2[p] = pkadd(a2[p], x2[p]);
    }
    float sq = 0.f;
#pragma unroll
    for (int p = 0; p < 4; ++p) {
        sq = fmaf(a2[p].x, a2[p].x, sq);
        sq = fmaf(a2[p].y, a2[p].y, sq);
    }
    sq = dpp_add8(sq);
    float gn = dr * sqrtf(sq);          // ||gnn||  (gnn = dr * a)
    float nrm = fmaxf(gn, 1e-12f);
    float scale = dr / nrm;             // Qn = a * scale
    if (l == 0) normv_s[wb] = nrm;
    unsigned ro = ((unsigned)r << 7) + l16;
    uint4 on;
    on.x = pack2(a2[0].x * scale, a2[0].y * scale);
    on.y = pack2(a2[1].x * scale, a2[1].y * scale);
    on.z = pack2(a2[2].x * scale, a2[2].y * scale);
    on.w = pack2(a2[3].x * scale, a2[3].y * scale);
    *(uint4*)((char*)Qn_ + ro) = on;
}

// merged score+fine, 8 rows/wave. Dot over pre-normalized Qn: sc = 0.5d+0.5.
// gnn[r] reconstructed as Qn[r]*normv. All 64 lanes store C/S/acc/fine.
__global__ __launch_bounds__(256) void score_fine_kernel(const u16* __restrict__ A_,
                                                         const u16* __restrict__ Qn_,
                                                         u16* __restrict__ C_,
                                                         u16* __restrict__ S_,
                                                         const float* __restrict__ normv_s,
                                                         const int4* __restrict__ srt,
                                                         const int* __restrict__ col_off,
                                                         float* __restrict__ out, int layer) {
    int w = (blockIdx.x * 256 + threadIdx.x) >> 6;
    if (w >= NW) return;
    int lane = threadIdx.x & 63;
    int g = lane >> 3, l = lane & 7;
    unsigned l16 = (unsigned)l * 16u;
    int wb = w * 8 + g;
    int4 q4 = srt[wb];
    int s = q4.x, t = q4.y;
    float dsr = __int_as_float(q4.z);
    int r = q4.w;
    float nrm = normv_s[wb];
    const char* pQn = (const char*)Qn_;
    const char* pA  = (const char*)A_;
    unsigned ro = ((unsigned)r << 7) + l16;
    uint4 qbn = *(const uint4*)(pQn + ro);
    f32x2 b2[4];
    unp8(qbn, b2);
    f32x2 z; z.x = 0.f; z.y = 0.f;
    f32x2 facc[4] = {z, z, z, z};
    float rowsum = 0.f;
#pragma unroll 2
    for (int j = s; j < t; ++j) {
        unsigned off = (unsigned)col_off[j];
        unsigned vo = off + l16;
        uint4 qx = *(const uint4*)(pQn + vo);
        uint4 qy = *(const uint4*)(pA + vo);
        f32x2 x2[4];
        unp8(qx, x2);
        f32x2 d2 = pkfma(b2[0], x2[0], z);
        d2 = pkfma(b2[1], x2[1], d2);
        d2 = pkfma(b2[2], x2[2], d2);
        d2 = pkfma(b2[3], x2[3], d2);
        float d = dpp_add8(d2.x + d2.y);   // group-uniform dot
        float sc = fmaf(d, 0.5f, 0.5f);
        rowsum += sc;
        f32x2 y2[4];
        unp8(qy, y2);
        f32x2 sc2; sc2.x = sc; sc2.y = sc;
#pragma unroll
        for (int p = 0; p < 4; ++p) facc[p] = pkfma(sc2, y2[p], facc[p]);
    }
    float di = rowsum > 0.f ? 1.f / rowsum : 0.f;
    float f[8] = {facc[0].x * di, facc[0].y * di, facc[1].x * di, facc[1].y * di,
                  facc[2].x * di, facc[2].y * di, facc[3].x * di, facc[3].y * di};
    float bb[8] = {b2[0].x, b2[0].y, b2[1].x, b2[1].y,
                   b2[2].x, b2[2].y, b2[3].x, b2[3].y};
    float cn[8];
#pragma unroll
    for (int k = 0; k < 8; ++k) cn[k] = fmaf(bb[k], nrm, f[k]);  // gnn + fine
    uint4 qn;
    qn.x = pack2(cn[0], cn[1]); qn.y = pack2(cn[2], cn[3]);
    qn.z = pack2(cn[4], cn[5]); qn.w = pack2(cn[6], cn[7]);
    *(uint4*)((char*)C_ + ro) = qn;
    if (layer != Ln - 1) {  // prescaled cur_new for next layer's spmm
        uint4 qs;
        qs.x = pack2(cn[0] * dsr, cn[1] * dsr);
        qs.y = pack2(cn[2] * dsr, cn[3] * dsr);
        qs.z = pack2(cn[4] * dsr, cn[5] * dsr);
        qs.w = pack2(cn[6] * dsr, cn[7] * dsr);
        *(uint4*)((char*)S_ + ro) = qs;
    }
    float* op = out + (size_t)r * D + l * 8;
    float4 a0 = ((float4*)op)[0], a1 = ((float4*)op)[1];
    a0.x += cn[0]; a0.y += cn[1]; a0.z += cn[2]; a0.w += cn[3];
    a1.x += cn[4]; a1.y += cn[5]; a1.z += cn[6]; a1.w += cn[7];
    ((float4*)op)[0] = a0;
    ((float4*)op)[1] = a1;
    size_t fo;
    if (r < Un)
        fo = (size_t)Nn * D + (size_t)layer * Un * D + (size_t)r * D + l * 8;
    else
        fo = (size_t)Nn * D + (size_t)Ln * Un * D + (size_t)layer * In * D
             + (size_t)(r - Un) * D + l * 8;
    f32x4 f0, f1;
    f0.x = f[0]; f0.y = f[1]; f0.z = f[2]; f0.w = f[3];
    f1.x = f[4]; f1.y = f[5]; f1.z = f[6]; f1.w = f[7];
    __builtin_nontemporal_store(f0, (f32x4*)(out + fo));
    __builtin_nontemporal_store(f1, (f32x4*)(out + fo) + 1);
}

}  // namespace

extern "C" void kernel_launch(void* const* d_in, const int* in_sizes, int n_in,
                              void* d_out, int out_size, void* d_ws, size_t ws_size,
                              hipStream_t stream) {
    const float* user_emb = (const float*)d_in[0];
    const float* item_emb = (const float*)d_in[1];
    const int* rows = (const int*)d_in[2];
    const int* cols = (const int*)d_in[3];
    float* out = (float*)d_out;

    char* ws = (char*)d_ws;
    size_t off = 0;
    auto alloc = [&](size_t bytes) -> void* {
        void* p = ws + off;
        off += (bytes + 255) & ~size_t(255);
        return p;
    };
    u16*   buf0    = (u16*)  alloc((size_t)Nn * D * 2);   // P: cur (plain)
    u16*   buf1    = (u16*)  alloc((size_t)Nn * D * 2);   // R: cur_new (plain)
    u16*   buf2    = (u16*)  alloc((size_t)Nn * D * 2);   // Qn: normalized gnn
    u16*   buf3    = (u16*)  alloc((size_t)Nn * D * 2);   // S: prescaled cur
    int*   col_off = (int*)  alloc((size_t)(En + 8) * 4); // byte offsets c*128
    int*   deg     = (int*)  alloc((size_t)Nn * 4);
    int*   row_ptr = (int*)  alloc((size_t)(Nn + 1) * 4);
    float* d_is    = (float*)alloc((size_t)Nn * 4);
    float* normv_s = (float*)alloc((size_t)Nn * 4);
    int4*  srt     = (int4*) alloc((size_t)Nn * 16);      // sorted row records
    int*   hp      = (int*)  alloc((size_t)DCAP * NB * 4);// per-block hists
    int*   bsum    = (int*)  alloc(4096);
    // eoff (8 MB) aliases buf2 (Qn): Qn first written by spmm_gnn layer 0,
    // strictly after fill_kernel has consumed eoff.
    int*   eoff    = (int*)buf2;
    (void)ws_size; (void)in_sizes; (void)n_in; (void)out_size;

    hipMemsetAsync(deg, 0, (size_t)Nn * 4, stream);

    const int EB = (En + 255) / 256;
    count_kernel<<<EB, 256, 0, stream>>>(rows, deg, eoff);
    scan_partial<<<NB, 256, 0, stream>>>(deg, d_is, bsum);
    scan_top<<<1, 256, 0, stream>>>(bsum, row_ptr);
    scan_final<<<NB, 256, 0, stream>>>(deg, bsum, row_ptr);
    hist_part<<<NB, 256, 0, stream>>>(deg, hp);
    hp_scan<<<1, 1024, 0, stream>>>(hp);
    fill_kernel<<<EB, 256, 0, stream>>>(rows, cols, row_ptr, eoff, col_off);
    perm_scatter<<<NB, 256, 0, stream>>>(deg, row_ptr, d_is, hp, srt);
    // init after scan_partial (needs d_is for the prescaled S0)
    init_kernel<<<(Nn * D / 4 + 255) / 256, 256, 0, stream>>>(user_emb, item_emb, d_is,
                                                              out, buf0, buf3);

    const int WB = (NW * 64 + 255) / 256;  // 4688 blocks, 4 waves/block, 8 rows/wave
    u16* P = buf0;  // cur (plain)
    u16* R = buf1;  // cur_new (plain)
    u16* Qn = buf2;
    u16* S  = buf3; // prescaled cur for spmm (rewritten by score each layer)
    for (int l = 0; l < Ln; ++l) {
        spmm_gnn<<<WB, 256, 0, stream>>>(S, Qn, srt, col_off, normv_s);
        score_fine_kernel<<<WB, 256, 0, stream>>>(P, Qn, R, S, normv_s, srt,
                                                  col_off, out, l);
        u16* tmp = P; P = R; R = tmp;  // cur_new becomes cur
    }
}